// Round 14
// baseline (409.550 us; speedup 1.0000x reference)
//
#include <hip/hip_runtime.h>
#include <hip/hip_bf16.h>

#define T_LEN 256
#define B_DIM 128
#define EMB 1024
#define HID 1024
#define NLAB 50
#define M_ROWS (T_LEN * B_DIM)   // 32768
#define N3H 3072
#define KT 16                    // 1024 / BK=64

typedef __attribute__((ext_vector_type(8))) short short8;
typedef __attribute__((ext_vector_type(4))) float f32x4;

// ---- helpers ----
static __device__ __forceinline__ ushort f2b(float x) {
    unsigned u = __builtin_bit_cast(unsigned, x);
    unsigned lsb = (u >> 16) & 1u;
    u += 0x7fffu + lsb;
    return (ushort)(u >> 16);
}
static __device__ __forceinline__ float b2f(ushort u) {
    unsigned v = ((unsigned)u) << 16;
    return __builtin_bit_cast(float, v);
}
static __device__ __forceinline__ void gload16(const ushort* g, ushort* l) {
    __builtin_amdgcn_global_load_lds(
        (const __attribute__((address_space(1))) unsigned int*)g,
        (__attribute__((address_space(3))) unsigned int*)l,
        16, 0, 0);
}
static __device__ __forceinline__ float fast_sigmoid(float y) {
    return 1.f / (1.f + __expf(-y));
}
static __device__ __forceinline__ float fast_tanh(float y) {
    float e = __expf(2.f * y);
    return (e - 1.f) / (e + 1.f);
}

// ---- kernel 1: Wt[n][k] = bf16(W[k][n]) only (gather is fused into GEMM) ----
__global__ __launch_bounds__(256) void transposeW(
    const float* __restrict__ W, ushort* __restrict__ Wt)
{
    __shared__ float tile[32][33];
    const int bx = blockIdx.x;                  // 96 n-tiles x 32 k-tiles
    const int n0 = (bx % 96) * 32, k0 = (bx / 96) * 32;
    const int tx = threadIdx.x & 31, ty = threadIdx.x >> 5;   // 32 x 8
#pragma unroll
    for (int j = 0; j < 32; j += 8)
        tile[ty + j][tx] = W[(size_t)(k0 + ty + j) * N3H + n0 + tx];
    __syncthreads();
#pragma unroll
    for (int j = 0; j < 32; j += 8)
        Wt[(size_t)(n0 + ty + j) * EMB + k0 + tx] = f2b(tile[tx][ty + j]);
}

// ---- kernel 2: 128x128 GEMM with FUSED embedding gather on the A side ----
// Structure = R8/R10 proven m97-style (BK=64, 4 waves, single-buffer,
// row-major [128][64] LDS + within-row granule-XOR, 0 bank conflicts).
// A-side: reg-staged gather — thread's chunk c maps to emb[sent[rowbase+row]]
// (f32), loaded as 2x float4, RNE-converted, ds_write_b128 to the SAME linear
// LDS offset as before (source-XOR mapping unchanged). B-side: global_load_lds.
__global__ __launch_bounds__(256) void gemm128(
    const int* __restrict__ sent, const float* __restrict__ emb,
    const ushort* __restrict__ Bt, const float* __restrict__ bias,
    ushort* __restrict__ zb, ushort* __restrict__ fb, ushort* __restrict__ ob)
{
    __shared__ ushort LA[128 * 64];   // 16 KB
    __shared__ ushort LB[128 * 64];   // 16 KB

    const int tid = threadIdx.x;
    const int lane = tid & 63;
    const int w = tid >> 6;
    const int wr = w >> 1, wc = w & 1;          // 2x2 wave grid, wave-tile 64x64
    const int l15 = lane & 15, lh = lane >> 4;

    const int wg = blockIdx.x;
    const ushort* Bb;
    const float* bptr;
    ushort* dst;
    int arowbase, rowbase, colbase;
    bool use_tanh;
    if (wg < 4096) {
        // XCD-chunked bijective swizzle (4096 % 8 == 0), nt-fastest:
        // 16 consecutive blocks on one XCD share the same A-panel (L2 reuse).
        const int w2 = (wg & 7) * 512 + (wg >> 3);
        const int mt = w2 >> 4, nt = w2 & 15;
        arowbase = mt * 128;
        Bb = Bt + (size_t)nt * 128 * EMB;
        bptr = bias + nt * 128;
        rowbase = mt * 128;
        if (nt < 8) { dst = zb; colbase = nt * 128; use_tanh = true; }
        else        { dst = fb; colbase = (nt - 8) * 128; use_tanh = false; }
    } else {
        // o-gate: last 128 rows x cols 2048 + q*128
        const int q = wg - 4096;
        arowbase = M_ROWS - 128;
        Bb = Bt + (size_t)(2048 + q * 128) * EMB;
        bptr = bias + 2048 + q * 128;
        rowbase = 0; colbase = q * 128;
        dst = ob; use_tanh = false;
    }

    // stage-side: 4 chunks per matrix per thread; chunk c = q*256 + tid,
    // row = c>>3 (0..127), LDS slot = c&7, source granule = (c&7)^(row&7).
    const float* gAf[4];                 // direct emb gather (f32)
    const ushort* gB[4];
    int dOf[4];
#pragma unroll
    for (int q = 0; q < 4; q++) {
        const int c = q * 256 + tid;
        const int row = c >> 3;
        const int gsrc = (c & 7) ^ (row & 7);
        gAf[q] = emb + (size_t)sent[arowbase + row] * EMB + gsrc * 8;
        gB[q] = Bb + (size_t)row * EMB + gsrc * 8;
        dOf[q] = c * 8;
    }

    // read-side base offsets (ushort units); frag mi at +mi*1024
    const int swz0 = (lh ^ (l15 & 7)) * 8;         // ks=0: octet lh
    const int swz1 = ((4 + lh) ^ (l15 & 7)) * 8;   // ks=1: octet 4+lh
    const int aRow = (wr * 64 + l15) * 64;
    const int bRow = (wc * 64 + l15) * 64;

    f32x4 acc[4][4] = {};

    for (int kk = 0; kk < KT; ++kk) {
        const int ko = kk * 64;
        // B staging: async global->LDS
        gload16(gB[0] + ko, LB + dOf[0]);
        gload16(gB[1] + ko, LB + dOf[1]);
        gload16(gB[2] + ko, LB + dOf[2]);
        gload16(gB[3] + ko, LB + dOf[3]);
        // A staging: gather f32 -> bf16 -> LDS (same layout as before)
#pragma unroll
        for (int q = 0; q < 4; q++) {
            float4 v0 = *(const float4*)(gAf[q] + ko);
            float4 v1 = *(const float4*)(gAf[q] + ko + 4);
            short8 o;
            o[0] = (short)f2b(v0.x); o[1] = (short)f2b(v0.y);
            o[2] = (short)f2b(v0.z); o[3] = (short)f2b(v0.w);
            o[4] = (short)f2b(v1.x); o[5] = (short)f2b(v1.y);
            o[6] = (short)f2b(v1.z); o[7] = (short)f2b(v1.w);
            *(short8*)(LA + dOf[q]) = o;
        }
        __syncthreads();

        // ks = 0
        {
            short8 a0 = *(const short8*)&LA[aRow + swz0];
            short8 a1 = *(const short8*)&LA[aRow + 1024 + swz0];
            short8 a2 = *(const short8*)&LA[aRow + 2048 + swz0];
            short8 a3 = *(const short8*)&LA[aRow + 3072 + swz0];
            short8 b0 = *(const short8*)&LB[bRow + swz0];
            short8 b1 = *(const short8*)&LB[bRow + 1024 + swz0];
            short8 b2 = *(const short8*)&LB[bRow + 2048 + swz0];
            short8 b3 = *(const short8*)&LB[bRow + 3072 + swz0];
#pragma unroll
            for (int mi = 0; mi < 4; mi++) {
                const short8 am = (mi == 0) ? a0 : (mi == 1) ? a1 : (mi == 2) ? a2 : a3;
                acc[mi][0] = __builtin_amdgcn_mfma_f32_16x16x32_bf16(am, b0, acc[mi][0], 0, 0, 0);
                acc[mi][1] = __builtin_amdgcn_mfma_f32_16x16x32_bf16(am, b1, acc[mi][1], 0, 0, 0);
                acc[mi][2] = __builtin_amdgcn_mfma_f32_16x16x32_bf16(am, b2, acc[mi][2], 0, 0, 0);
                acc[mi][3] = __builtin_amdgcn_mfma_f32_16x16x32_bf16(am, b3, acc[mi][3], 0, 0, 0);
            }
        }
        // ks = 1
        {
            short8 a0 = *(const short8*)&LA[aRow + swz1];
            short8 a1 = *(const short8*)&LA[aRow + 1024 + swz1];
            short8 a2 = *(const short8*)&LA[aRow + 2048 + swz1];
            short8 a3 = *(const short8*)&LA[aRow + 3072 + swz1];
            short8 b0 = *(const short8*)&LB[bRow + swz1];
            short8 b1 = *(const short8*)&LB[bRow + 1024 + swz1];
            short8 b2 = *(const short8*)&LB[bRow + 2048 + swz1];
            short8 b3 = *(const short8*)&LB[bRow + 3072 + swz1];
#pragma unroll
            for (int mi = 0; mi < 4; mi++) {
                const short8 am = (mi == 0) ? a0 : (mi == 1) ? a1 : (mi == 2) ? a2 : a3;
                acc[mi][0] = __builtin_amdgcn_mfma_f32_16x16x32_bf16(am, b0, acc[mi][0], 0, 0, 0);
                acc[mi][1] = __builtin_amdgcn_mfma_f32_16x16x32_bf16(am, b1, acc[mi][1], 0, 0, 0);
                acc[mi][2] = __builtin_amdgcn_mfma_f32_16x16x32_bf16(am, b2, acc[mi][2], 0, 0, 0);
                acc[mi][3] = __builtin_amdgcn_mfma_f32_16x16x32_bf16(am, b3, acc[mi][3], 0, 0, 0);
            }
        }
        __syncthreads();
    }

    // epilogue: bias + activation + bf16 stores
#pragma unroll
    for (int mi = 0; mi < 4; mi++) {
#pragma unroll
        for (int ni = 0; ni < 4; ni++) {
            const int nb = wc * 64 + ni * 16 + l15;
            const float bv = bptr[nb];
            const int rl = wr * 64 + mi * 16 + lh * 4;
#pragma unroll
            for (int r = 0; r < 4; r++) {
                float y = acc[mi][ni][r] + bv;
                float a = use_tanh ? fast_tanh(y) : fast_sigmoid(y);
                dst[(size_t)(rowbase + rl + r) * HID + colbase + nb] = f2b(a);
            }
        }
    }
}

// ---- kernel 3: fo-pool scan over T; h = o_last * c_last ----
__global__ __launch_bounds__(256) void fo_pool(
    const unsigned* __restrict__ z32, const unsigned* __restrict__ fz32,
    const unsigned* __restrict__ o32, float* __restrict__ hbuf)
{
    const int p = blockIdx.x * 256 + threadIdx.x;  // pairs of h
    float c0 = 0.f, c1 = 0.f;
#pragma unroll 8
    for (int t = 0; t < T_LEN; ++t) {
        unsigned zz = z32[(size_t)t * (B_DIM * HID / 2) + p];
        unsigned ff = fz32[(size_t)t * (B_DIM * HID / 2) + p];
        float z0 = b2f((ushort)(zz & 0xffffu)), z1 = b2f((ushort)(zz >> 16));
        float f0 = b2f((ushort)(ff & 0xffffu)), f1 = b2f((ushort)(ff >> 16));
        c0 += f0 * (z0 - c0);
        c1 += f1 * (z1 - c1);
    }
    unsigned oo = o32[p];
    float o0 = b2f((ushort)(oo & 0xffffu)), o1 = b2f((ushort)(oo >> 16));
    hbuf[2 * p]     = o0 * c0;
    hbuf[2 * p + 1] = o1 * c1;
}

// ---- kernel 4: logits = h @ Wout + bout; log_softmax ----
__global__ __launch_bounds__(64) void classify(
    const float* __restrict__ hbuf, const float* __restrict__ Wout,
    const float* __restrict__ bout, float* __restrict__ out)
{
    __shared__ float hs[HID];
    const int b = blockIdx.x, l = threadIdx.x;
#pragma unroll
    for (int j = 0; j < HID; j += 64) hs[j + l] = hbuf[(size_t)b * HID + j + l];
    __syncthreads();
    float acc = -1e30f;
    if (l < NLAB) {
        float s = bout[l];
#pragma unroll 4
        for (int e = 0; e < HID; e++) s += hs[e] * Wout[(size_t)e * NLAB + l];
        acc = s;
    }
    float m = acc;
#pragma unroll
    for (int off = 32; off; off >>= 1) m = fmaxf(m, __shfl_xor(m, off));
    float ex = (l < NLAB) ? expf(acc - m) : 0.f;
    float sum = ex;
#pragma unroll
    for (int off = 32; off; off >>= 1) sum += __shfl_xor(sum, off);
    if (l < NLAB) out[(size_t)b * NLAB + l] = acc - m - logf(sum);
}

extern "C" void kernel_launch(void* const* d_in, const int* in_sizes, int n_in,
                              void* d_out, int out_size, void* d_ws, size_t ws_size,
                              hipStream_t stream) {
    const int* sent = (const int*)d_in[0];
    const float* emb = (const float*)d_in[1];
    const float* W = (const float*)d_in[2];
    const float* bias = (const float*)d_in[3];
    const float* Wout = (const float*)d_in[4];
    const float* bout = (const float*)d_in[5];
    float* out = (float*)d_out;

    ushort* Wt = (ushort*)d_ws;                      // 3072*1024 bf16
    ushort* zb = Wt + (size_t)N3H * EMB;             // 32768*1024 bf16
    ushort* fb = zb + (size_t)M_ROWS * HID;          // 32768*1024 bf16
    ushort* ob = fb + (size_t)M_ROWS * HID;          // 128*1024 bf16
    float* hb = (float*)(ob + (size_t)B_DIM * HID);  // 128*1024 f32

    hipLaunchKernelGGL(transposeW, dim3(3072), dim3(256), 0, stream, W, Wt);
    hipLaunchKernelGGL(gemm128, dim3(4096 + 8), dim3(256), 0, stream,
                       sent, emb, Wt, bias, zb, fb, ob);
    hipLaunchKernelGGL(fo_pool, dim3(B_DIM * HID / 2 / 256), dim3(256), 0, stream,
                       (const unsigned*)zb, (const unsigned*)fb,
                       (const unsigned*)ob, hb);
    hipLaunchKernelGGL(classify, dim3(B_DIM), dim3(64), 0, stream,
                       hb, Wout, bout, out);
}

// Round 15
// 324.656 us; speedup vs baseline: 1.2615x; 1.2615x over previous
//
#include <hip/hip_runtime.h>
#include <hip/hip_bf16.h>

#define T_LEN 256
#define B_DIM 128
#define EMB 1024
#define HID 1024
#define NLAB 50
#define M_ROWS (T_LEN * B_DIM)   // 32768
#define N3H 3072
#define KT 16                    // 1024 / BK=64

typedef __attribute__((ext_vector_type(8))) short short8;
typedef __attribute__((ext_vector_type(4))) float f32x4;

// ---- helpers ----
static __device__ __forceinline__ ushort f2b(float x) {
    unsigned u = __builtin_bit_cast(unsigned, x);
    unsigned lsb = (u >> 16) & 1u;
    u += 0x7fffu + lsb;
    return (ushort)(u >> 16);
}
static __device__ __forceinline__ float b2f(ushort u) {
    unsigned v = ((unsigned)u) << 16;
    return __builtin_bit_cast(float, v);
}
static __device__ __forceinline__ void gload16(const ushort* g, ushort* l) {
    __builtin_amdgcn_global_load_lds(
        (const __attribute__((address_space(1))) unsigned int*)g,
        (__attribute__((address_space(3))) unsigned int*)l,
        16, 0, 0);
}
static __device__ __forceinline__ float fast_sigmoid(float y) {
    return 1.f / (1.f + __expf(-y));
}
static __device__ __forceinline__ float fast_tanh(float y) {
    float e = __expf(2.f * y);
    return (e - 1.f) / (e + 1.f);
}

// ---- kernel 1: gather+convert AND W-transpose, fused into one launch ----
// Blocks 0..2047: x = bf16(emb[sentence]) (16 rows each).
// Blocks 2048..5119: Wt[n][k] = bf16(W[k][n]) (32x32 tile each).
__global__ __launch_bounds__(256) void prep(
    const int* __restrict__ sent, const float* __restrict__ emb,
    const float* __restrict__ W,
    ushort* __restrict__ xb, ushort* __restrict__ Wt)
{
    __shared__ float tile[32][33];
    const int wg = blockIdx.x;
    if (wg < 2048) {
        const int row = wg * 16 + (threadIdx.x >> 4);
        const int seg = threadIdx.x & 15;
        const size_t src = (size_t)sent[row] * EMB;
        const float4* ep = (const float4*)(emb + src);
        ushort4* op = (ushort4*)(xb + (size_t)row * EMB);
#pragma unroll
        for (int j = 0; j < 16; j++) {
            float4 v = ep[seg + j * 16];
            ushort4 o;
            o.x = f2b(v.x); o.y = f2b(v.y); o.z = f2b(v.z); o.w = f2b(v.w);
            op[seg + j * 16] = o;
        }
    } else {
        const int bx = wg - 2048;               // 96 n-tiles x 32 k-tiles
        const int n0 = (bx % 96) * 32, k0 = (bx / 96) * 32;
        const int tx = threadIdx.x & 31, ty = threadIdx.x >> 5;   // 32 x 8
#pragma unroll
        for (int j = 0; j < 32; j += 8)
            tile[ty + j][tx] = W[(size_t)(k0 + ty + j) * N3H + n0 + tx];
        __syncthreads();
#pragma unroll
        for (int j = 0; j < 32; j += 8)
            Wt[(size_t)(n0 + ty + j) * EMB + k0 + tx] = f2b(tile[tx][ty + j]);
    }
}

// ---- kernel 2: m97-structure 128x128 GEMM, BK=64, 4 waves, single-buffer ----
// (R8/R10 configuration, verified: ~179us, MfmaUtil 34-35%, 0 bank conflicts.)
// LDS: row-major [128][64] bf16 per matrix (16 KB each). Rows are 128B = 8
// granules of 16B; granule g of row r stored at slot g^(r&7) (involution).
// Staging: linear LDS dest (chunk c = row*8+slot), global source granule
// (c&7)^(row&7) -> permutation stays within the row's 128B, coalesced.
// Read: lane (l15,lh), k-octet o=ks*4+lh at row R: slot o^(R&7). R&7==l15&7,
// so swizzle term is mi/ni-independent. Conflict-free (0 measured).
// Occupancy ~5 blocks/CU (32KB LDS, 76 VGPR) provides TLP latency hiding.
__global__ __launch_bounds__(256) void gemm128(
    const ushort* __restrict__ A, const ushort* __restrict__ Bt,
    const float* __restrict__ bias,
    ushort* __restrict__ zb, ushort* __restrict__ fb, ushort* __restrict__ ob)
{
    __shared__ ushort LA[128 * 64];   // 16 KB
    __shared__ ushort LB[128 * 64];   // 16 KB

    const int tid = threadIdx.x;
    const int lane = tid & 63;
    const int w = tid >> 6;
    const int wr = w >> 1, wc = w & 1;          // 2x2 wave grid, wave-tile 64x64
    const int l15 = lane & 15, lh = lane >> 4;

    const int wg = blockIdx.x;
    const ushort *Ab, *Bb;
    const float* bptr;
    ushort* dst;
    int rowbase, colbase;
    bool use_tanh;
    if (wg < 4096) {
        // XCD-chunked bijective swizzle (4096 % 8 == 0), nt-fastest:
        // 16 consecutive blocks on one XCD share the same A-panel (L2 reuse).
        const int w2 = (wg & 7) * 512 + (wg >> 3);
        const int mt = w2 >> 4, nt = w2 & 15;
        Ab = A + (size_t)mt * 128 * EMB;
        Bb = Bt + (size_t)nt * 128 * EMB;
        bptr = bias + nt * 128;
        rowbase = mt * 128;
        if (nt < 8) { dst = zb; colbase = nt * 128; use_tanh = true; }
        else        { dst = fb; colbase = (nt - 8) * 128; use_tanh = false; }
    } else {
        // o-gate: last 128 rows x cols 2048 + q*128 (all rows valid)
        const int q = wg - 4096;
        Ab = A + (size_t)(M_ROWS - 128) * EMB;
        Bb = Bt + (size_t)(2048 + q * 128) * EMB;
        bptr = bias + 2048 + q * 128;
        rowbase = 0; colbase = q * 128;
        dst = ob; use_tanh = false;
    }

    // stage-side: 4 chunks per matrix per thread; chunk c = q*256 + tid
    const ushort* gA[4];
    const ushort* gB[4];
    int dOf[4];
#pragma unroll
    for (int q = 0; q < 4; q++) {
        const int c = q * 256 + tid;
        const int row = c >> 3;
        const int gsrc = (c & 7) ^ (row & 7);
        gA[q] = Ab + (size_t)row * EMB + gsrc * 8;
        gB[q] = Bb + (size_t)row * EMB + gsrc * 8;
        dOf[q] = c * 8;
    }

    // read-side base offsets (ushort units); frag mi at +mi*1024
    const int swz0 = (lh ^ (l15 & 7)) * 8;         // ks=0: octet lh
    const int swz1 = ((4 + lh) ^ (l15 & 7)) * 8;   // ks=1: octet 4+lh
    const int aRow = (wr * 64 + l15) * 64;
    const int bRow = (wc * 64 + l15) * 64;

    f32x4 acc[4][4] = {};

    for (int kk = 0; kk < KT; ++kk) {
        const int ko = kk * 64;
        gload16(gA[0] + ko, LA + dOf[0]);
        gload16(gA[1] + ko, LA + dOf[1]);
        gload16(gA[2] + ko, LA + dOf[2]);
        gload16(gA[3] + ko, LA + dOf[3]);
        gload16(gB[0] + ko, LB + dOf[0]);
        gload16(gB[1] + ko, LB + dOf[1]);
        gload16(gB[2] + ko, LB + dOf[2]);
        gload16(gB[3] + ko, LB + dOf[3]);
        __syncthreads();

        // ks = 0
        {
            short8 a0 = *(const short8*)&LA[aRow + swz0];
            short8 a1 = *(const short8*)&LA[aRow + 1024 + swz0];
            short8 a2 = *(const short8*)&LA[aRow + 2048 + swz0];
            short8 a3 = *(const short8*)&LA[aRow + 3072 + swz0];
            short8 b0 = *(const short8*)&LB[bRow + swz0];
            short8 b1 = *(const short8*)&LB[bRow + 1024 + swz0];
            short8 b2 = *(const short8*)&LB[bRow + 2048 + swz0];
            short8 b3 = *(const short8*)&LB[bRow + 3072 + swz0];
#pragma unroll
            for (int mi = 0; mi < 4; mi++) {
                const short8 am = (mi == 0) ? a0 : (mi == 1) ? a1 : (mi == 2) ? a2 : a3;
                acc[mi][0] = __builtin_amdgcn_mfma_f32_16x16x32_bf16(am, b0, acc[mi][0], 0, 0, 0);
                acc[mi][1] = __builtin_amdgcn_mfma_f32_16x16x32_bf16(am, b1, acc[mi][1], 0, 0, 0);
                acc[mi][2] = __builtin_amdgcn_mfma_f32_16x16x32_bf16(am, b2, acc[mi][2], 0, 0, 0);
                acc[mi][3] = __builtin_amdgcn_mfma_f32_16x16x32_bf16(am, b3, acc[mi][3], 0, 0, 0);
            }
        }
        // ks = 1
        {
            short8 a0 = *(const short8*)&LA[aRow + swz1];
            short8 a1 = *(const short8*)&LA[aRow + 1024 + swz1];
            short8 a2 = *(const short8*)&LA[aRow + 2048 + swz1];
            short8 a3 = *(const short8*)&LA[aRow + 3072 + swz1];
            short8 b0 = *(const short8*)&LB[bRow + swz1];
            short8 b1 = *(const short8*)&LB[bRow + 1024 + swz1];
            short8 b2 = *(const short8*)&LB[bRow + 2048 + swz1];
            short8 b3 = *(const short8*)&LB[bRow + 3072 + swz1];
#pragma unroll
            for (int mi = 0; mi < 4; mi++) {
                const short8 am = (mi == 0) ? a0 : (mi == 1) ? a1 : (mi == 2) ? a2 : a3;
                acc[mi][0] = __builtin_amdgcn_mfma_f32_16x16x32_bf16(am, b0, acc[mi][0], 0, 0, 0);
                acc[mi][1] = __builtin_amdgcn_mfma_f32_16x16x32_bf16(am, b1, acc[mi][1], 0, 0, 0);
                acc[mi][2] = __builtin_amdgcn_mfma_f32_16x16x32_bf16(am, b2, acc[mi][2], 0, 0, 0);
                acc[mi][3] = __builtin_amdgcn_mfma_f32_16x16x32_bf16(am, b3, acc[mi][3], 0, 0, 0);
            }
        }
        __syncthreads();
    }

    // epilogue: bias + activation + bf16 stores
#pragma unroll
    for (int mi = 0; mi < 4; mi++) {
#pragma unroll
        for (int ni = 0; ni < 4; ni++) {
            const int nb = wc * 64 + ni * 16 + l15;
            const float bv = bptr[nb];
            const int rl = wr * 64 + mi * 16 + lh * 4;
#pragma unroll
            for (int r = 0; r < 4; r++) {
                float y = acc[mi][ni][r] + bv;
                float a = use_tanh ? fast_tanh(y) : fast_sigmoid(y);
                dst[(size_t)(rowbase + rl + r) * HID + colbase + nb] = f2b(a);
            }
        }
    }
}

// ---- kernel 3: fo-pool scan over T; h = o_last * c_last ----
__global__ __launch_bounds__(256) void fo_pool(
    const unsigned* __restrict__ z32, const unsigned* __restrict__ fz32,
    const unsigned* __restrict__ o32, float* __restrict__ hbuf)
{
    const int p = blockIdx.x * 256 + threadIdx.x;  // pairs of h
    float c0 = 0.f, c1 = 0.f;
#pragma unroll 8
    for (int t = 0; t < T_LEN; ++t) {
        unsigned zz = z32[(size_t)t * (B_DIM * HID / 2) + p];
        unsigned ff = fz32[(size_t)t * (B_DIM * HID / 2) + p];
        float z0 = b2f((ushort)(zz & 0xffffu)), z1 = b2f((ushort)(zz >> 16));
        float f0 = b2f((ushort)(ff & 0xffffu)), f1 = b2f((ushort)(ff >> 16));
        c0 += f0 * (z0 - c0);
        c1 += f1 * (z1 - c1);
    }
    unsigned oo = o32[p];
    float o0 = b2f((ushort)(oo & 0xffffu)), o1 = b2f((ushort)(oo >> 16));
    hbuf[2 * p]     = o0 * c0;
    hbuf[2 * p + 1] = o1 * c1;
}

// ---- kernel 4: logits = h @ Wout + bout; log_softmax ----
__global__ __launch_bounds__(64) void classify(
    const float* __restrict__ hbuf, const float* __restrict__ Wout,
    const float* __restrict__ bout, float* __restrict__ out)
{
    __shared__ float hs[HID];
    const int b = blockIdx.x, l = threadIdx.x;
#pragma unroll
    for (int j = 0; j < HID; j += 64) hs[j + l] = hbuf[(size_t)b * HID + j + l];
    __syncthreads();
    float acc = -1e30f;
    if (l < NLAB) {
        float s = bout[l];
#pragma unroll 4
        for (int e = 0; e < HID; e++) s += hs[e] * Wout[(size_t)e * NLAB + l];
        acc = s;
    }
    float m = acc;
#pragma unroll
    for (int off = 32; off; off >>= 1) m = fmaxf(m, __shfl_xor(m, off));
    float ex = (l < NLAB) ? expf(acc - m) : 0.f;
    float sum = ex;
#pragma unroll
    for (int off = 32; off; off >>= 1) sum += __shfl_xor(sum, off);
    if (l < NLAB) out[(size_t)b * NLAB + l] = acc - m - logf(sum);
}

extern "C" void kernel_launch(void* const* d_in, const int* in_sizes, int n_in,
                              void* d_out, int out_size, void* d_ws, size_t ws_size,
                              hipStream_t stream) {
    const int* sent = (const int*)d_in[0];
    const float* emb = (const float*)d_in[1];
    const float* W = (const float*)d_in[2];
    const float* bias = (const float*)d_in[3];
    const float* Wout = (const float*)d_in[4];
    const float* bout = (const float*)d_in[5];
    float* out = (float*)d_out;

    ushort* xb = (ushort*)d_ws;                      // 32768*1024 bf16
    ushort* Wt = xb + (size_t)M_ROWS * EMB;          // 3072*1024 bf16
    ushort* zb = Wt + (size_t)N3H * EMB;             // 32768*1024 bf16
    ushort* fb = zb + (size_t)M_ROWS * HID;          // 32768*1024 bf16
    ushort* ob = fb + (size_t)M_ROWS * HID;          // 128*1024 bf16
    float* hb = (float*)(ob + (size_t)B_DIM * HID);  // 128*1024 f32

    hipLaunchKernelGGL(prep, dim3(2048 + 3072), dim3(256), 0, stream,
                       sent, emb, W, xb, Wt);
    hipLaunchKernelGGL(gemm128, dim3(4096 + 8), dim3(256), 0, stream,
                       xb, Wt, bias, zb, fb, ob);
    hipLaunchKernelGGL(fo_pool, dim3(B_DIM * HID / 2 / 256), dim3(256), 0, stream,
                       (const unsigned*)zb, (const unsigned*)fb,
                       (const unsigned*)ob, hb);
    hipLaunchKernelGGL(classify, dim3(B_DIM), dim3(64), 0, stream,
                       hb, Wout, bout, out);
}